// Round 4
// baseline (493.033 us; speedup 1.0000x reference)
//
#include <hip/hip_runtime.h>

// HierarchicalMemory v6: 1 block/CU mega-cache — 96 rows in VGPRs + 94 rows
// in LDS (190/400 rows on-chip post-clip), packed-fp32 VALU, 2-deep prefetch.
//   M[p,q] = clip(F*Mp[p,q] + (LR*a[p])*b[q], -1, 1), masked block-triangular;
//   5 attractor iterations, frozen-row schedule Rt={400,340,280,200,100}.
// v5 post-mortem: iters 1-4 are bound by the 337 MB L3 re-read stream; v5's
// 2-block config capped on-chip storage at 78 rows. v6 trades occupancy
// (16->8 waves/CU) for capacity: VGPR cap 256 -> rA/rB hold rows [0,96)
// (block-0, full-width, c4beg=0); LDS 155.2KB holds rows [96,190) post-clip
// (masked lanes stored as 0). Iters 3-4 run ~fully on-chip; iters 1-2 stream
// only rows [190,R) = 64 MB total. Iter 0 stays HBM-BW-bound (issue ~3.3us
// << 31.5us read time), so halved occupancy doesn't hurt it.
// Lane l owns columns [4l..4l+3] and [256+4l..256+4l+3]; reduce = 6 DPP adds.

#define PDIM 400
#define RREG 12             // register-cached rows: [0, 8*RREG) = [0,96)
#define LROW0 96
#define LROWN 190           // LDS-cached rows [96,190): 94 rows * 1600B = 150.4KB
#define FORGET 0.9999f
#define LRATE  0.5f
#define DECAY  0.8f
#define SLOPE  0.01f

typedef float f32x2 __attribute__((ext_vector_type(2)));
union V4 { float4 f4; f32x2 h2[2]; };

__device__ __forceinline__ float leaky_clip(float x) {
    x = fminf(fmaxf(x, -1.0f), 1.0f);
    return x > 0.0f ? x : SLOPE * x;
}
__device__ __forceinline__ float clamp1(float x) {   // -> v_med3_f32
    return fminf(fmaxf(x, -1.0f), 1.0f);
}
__device__ __forceinline__ f32x2 pk_mul(f32x2 a, f32x2 b) {
    f32x2 d;
    asm("v_pk_mul_f32 %0, %1, %2" : "=v"(d) : "v"(a), "v"(b));
    return d;
}
__device__ __forceinline__ f32x2 pk_fma(f32x2 a, f32x2 b, f32x2 c) {
    f32x2 d;
    asm("v_pk_fma_f32 %0, %1, %2, %3" : "=v"(d) : "v"(a), "v"(b), "v"(c));
    return d;
}
__device__ __forceinline__ f32x2 clamp2(f32x2 x) {
    x.x = clamp1(x.x); x.y = clamp1(x.y); return x;
}

// first masked f4-chunk of row p (chunk = 4-float column group)
__device__ __forceinline__ int c4beg(int p) {
    return (p < 100) ? 0 : (p < 200) ? 25 : (p < 280) ? 50 : (p < 340) ? 70 : 85;
}

// wave64 sum via DPP: stays on the VALU pipe (no ds_swizzle / LDS traffic).
__device__ __forceinline__ float wave_sum(float x) {
    x += __int_as_float(__builtin_amdgcn_update_dpp(0, __float_as_int(x), 0xB1,  0xf, 0xf, true));
    x += __int_as_float(__builtin_amdgcn_update_dpp(0, __float_as_int(x), 0x4E,  0xf, 0xf, true));
    x += __int_as_float(__builtin_amdgcn_update_dpp(0, __float_as_int(x), 0x141, 0xf, 0xf, true));
    x += __int_as_float(__builtin_amdgcn_update_dpp(0, __float_as_int(x), 0x140, 0xf, 0xf, true));
    x += __int_as_float(__builtin_amdgcn_update_dpp(0, __float_as_int(x), 0x142, 0xf, 0xf, true));
    x += __int_as_float(__builtin_amdgcn_update_dpp(0, __float_as_int(x), 0x143, 0xf, 0xf, true));
    return __int_as_float(__builtin_amdgcn_readlane(__float_as_int(x), 63));
}

// predicated masked row load (global), zeros outside mask / past R
__device__ __forceinline__ void load_row(const float* __restrict__ Mb,
                                         int p, int R, int l,
                                         int& c4, V4& A, V4& B) {
    A.f4 = make_float4(0.f, 0.f, 0.f, 0.f);
    B.f4 = A.f4;
    c4 = 0;
    if (p < R) {
        c4 = c4beg(p);
        const float* __restrict__ row = Mb + (size_t)p * PDIM;
        if (l >= c4)                A.f4 = *(const float4*)(row + 4 * l);
        if (l < 36 && 64 + l >= c4) B.f4 = *(const float4*)(row + 256 + 4 * l);
    }
}

__global__ __launch_bounds__(512, 2)
void hier_mem_kernel(const float* __restrict__ M_prev,
                     const float* __restrict__ p_inf,
                     const float* __restrict__ p_gen,
                     const float* __restrict__ query,
                     float* __restrict__ out)
{
    __shared__ float s_mc[LROWN - LROW0][PDIM];   // 150,400 B post-clip M cache
    __shared__ float s_h[2][PDIM];
    __shared__ float s_la[PDIM];

    const int b   = blockIdx.x;
    const int tid = threadIdx.x;
    const int l   = tid & 63;   // lane
    const int wid = tid >> 6;   // wave 0..7
    const float* __restrict__ Mb = M_prev + (size_t)b * PDIM * PDIM;

    if (tid < PDIM) {
        const float pi = p_inf[b * PDIM + tid];
        const float pg = p_gen[b * PDIM + tid];
        s_la[tid]   = LRATE * (pi - pg);
        s_h[0][tid] = leaky_clip(query[b * PDIM + tid]);
    }

    // register-resident b-vector for this lane's fixed columns
    const float4 z4 = make_float4(0.f, 0.f, 0.f, 0.f);
    const float4* __restrict__ pi4 = (const float4*)(p_inf + (size_t)b * PDIM);
    const float4* __restrict__ pg4 = (const float4*)(p_gen + (size_t)b * PDIM);
    V4 vA, vB; vB.f4 = z4;
    {
        const float4 x = pi4[l], y = pg4[l];
        vA.f4 = make_float4(x.x + y.x, x.y + y.y, x.z + y.z, x.w + y.w);
        if (l < 36) {
            const float4 u = pi4[64 + l], v = pg4[64 + l];
            vB.f4 = make_float4(u.x + v.x, u.y + v.y, u.z + v.z, u.w + v.w);
        }
    }
    const f32x2 F2 = {FORGET, FORGET};

    V4 rA[RREG], rB[RREG];   // per-wave register row cache (rows wid+8k, k<RREG)

    __syncthreads();

    // ---------- iteration 0: stream all 400 rows; fill reg + LDS caches ----------
    {
        const float* __restrict__ hcur = s_h[0];
        float* __restrict__ hnew = s_h[1];
        V4 hA, hB; hB.f4 = z4;
        hA.f4 = *(const float4*)(hcur + 4 * l);
        if (l < 36) hB.f4 = *(const float4*)(hcur + 256 + 4 * l);

        int p = wid;
        int c0, c1; V4 A0, B0, A1, B1;
        load_row(Mb, p,     PDIM, l, c0, A0, B0);
        load_row(Mb, p + 8, PDIM, l, c1, A1, B1);

        // rows [0,96): compute + fill register cache (static indices).
        // All these rows have c4beg==0; B inputs are zero for lanes >= 36,
        // so the unpredicated Hebbian yields mB = clamp(0 + la*0) = 0 there.
        #pragma unroll
        for (int k = 0; k < RREG; ++k) {
            int c2; V4 A2, B2;
            load_row(Mb, p + 16, PDIM, l, c2, A2, B2);

            const float la = s_la[p];
            const f32x2 la2 = {la, la};
            V4 mA, mB;
            mA.h2[0] = clamp2(pk_fma(F2, A0.h2[0], pk_mul(la2, vA.h2[0])));
            mA.h2[1] = clamp2(pk_fma(F2, A0.h2[1], pk_mul(la2, vA.h2[1])));
            mB.h2[0] = clamp2(pk_fma(F2, B0.h2[0], pk_mul(la2, vB.h2[0])));
            mB.h2[1] = clamp2(pk_fma(F2, B0.h2[1], pk_mul(la2, vB.h2[1])));
            rA[k] = mA; rB[k] = mB;

            f32x2 acc2 = pk_fma(mA.h2[0], hA.h2[0],
                         pk_fma(mA.h2[1], hA.h2[1],
                         pk_fma(mB.h2[0], hB.h2[0],
                         pk_mul(mB.h2[1], hB.h2[1]))));
            const float tot = wave_sum(acc2.x + acc2.y);
            if (l == 0) {
                hnew[p] = leaky_clip(fmaf(DECAY, hcur[p], tot));
            }
            p += 8; c0 = c1; A0 = A1; B0 = B1; c1 = c2; A1 = A2; B1 = B2;
        }

        // rows [96,400): stream; write LDS cache for p < 190 (masked lanes
        // store 0 because mA/mB stay z4 outside the predicates)
        while (p < PDIM) {
            int c2; V4 A2, B2;
            load_row(Mb, p + 16, PDIM, l, c2, A2, B2);

            const float la = s_la[p];
            const f32x2 la2 = {la, la};
            f32x2 acc2 = {0.f, 0.f};
            V4 mA, mB; mA.f4 = z4; mB.f4 = z4;
            if (l >= c0) {
                mA.h2[0] = clamp2(pk_fma(F2, A0.h2[0], pk_mul(la2, vA.h2[0])));
                mA.h2[1] = clamp2(pk_fma(F2, A0.h2[1], pk_mul(la2, vA.h2[1])));
                acc2 = pk_fma(mA.h2[0], hA.h2[0], acc2);
                acc2 = pk_fma(mA.h2[1], hA.h2[1], acc2);
            }
            if (l < 36 && 64 + l >= c0) {
                mB.h2[0] = clamp2(pk_fma(F2, B0.h2[0], pk_mul(la2, vB.h2[0])));
                mB.h2[1] = clamp2(pk_fma(F2, B0.h2[1], pk_mul(la2, vB.h2[1])));
                acc2 = pk_fma(mB.h2[0], hB.h2[0], acc2);
                acc2 = pk_fma(mB.h2[1], hB.h2[1], acc2);
            }
            if (p < LROWN) {
                *(float4*)&s_mc[p - LROW0][4 * l] = mA.f4;
                if (l < 36) *(float4*)&s_mc[p - LROW0][256 + 4 * l] = mB.f4;
            }

            const float tot = wave_sum(acc2.x + acc2.y);
            if (l == 0) {
                hnew[p] = leaky_clip(fmaf(DECAY, hcur[p], tot));
            }

            p += 8; c0 = c1; A0 = A1; B0 = B1; c1 = c2; A1 = A2; B1 = B2;
        }
        __syncthreads();   // R=400: no frozen rows
    }

    // ---------- iterations 1..4: reg rows + LDS rows + streamed tail ----------
    int cur = 1;
    const int Rt[4] = {340, 280, 200, 100};
    #pragma unroll
    for (int t = 0; t < 4; ++t) {
        const int R = Rt[t];
        const float* __restrict__ hcur = s_h[cur];
        float* __restrict__ hnew = s_h[cur ^ 1];

        V4 hA, hB; hB.f4 = z4;
        hA.f4 = *(const float4*)(hcur + 4 * l);
        if (l < 36) hB.f4 = *(const float4*)(hcur + 256 + 4 * l);

        // kick off 2-deep global prefetch for the streamed tail FIRST
        // (load_row self-guards against p >= R, so iters 3-4 load nothing)
        int sp = LROWN + wid;
        int c0, c1; V4 A0, B0, A1, B1;
        load_row(Mb, sp,     R, l, c0, A0, B0);
        load_row(Mb, sp + 8, R, l, c1, A1, B1);

        // register-cached rows [0,96): pure VALU, 12 independent dot chains.
        // All rows < 100 <= R, so every visit is active in every iteration.
        #pragma unroll
        for (int k = 0; k < RREG; ++k) {
            const int p = wid + 8 * k;
            f32x2 acc2 = pk_fma(rA[k].h2[0], hA.h2[0],
                         pk_fma(rA[k].h2[1], hA.h2[1],
                         pk_fma(rB[k].h2[0], hB.h2[0],
                         pk_mul(rB[k].h2[1], hB.h2[1]))));
            const float tot = wave_sum(acc2.x + acc2.y);
            if (l == 0) {
                hnew[p] = leaky_clip(fmaf(DECAY, hcur[p], tot));
            }
        }

        // LDS-cached rows [96, min(190,R)): post-clip M, dot only, 1-ahead
        {
            const int Lend = (R < LROWN) ? R : LROWN;
            int p = LROW0 + wid;
            V4 KA, KB; KB.f4 = z4;
            KA.f4 = *(const float4*)&s_mc[p - LROW0][4 * l];
            if (l < 36) KB.f4 = *(const float4*)&s_mc[p - LROW0][256 + 4 * l];
            while (p < Lend) {
                const int pn = p + 8;
                V4 NA, NB; NA.f4 = z4; NB.f4 = z4;
                if (pn < Lend) {
                    NA.f4 = *(const float4*)&s_mc[pn - LROW0][4 * l];
                    if (l < 36) NB.f4 = *(const float4*)&s_mc[pn - LROW0][256 + 4 * l];
                }
                // masked lanes hold 0 in the cache -> unconditional dot is safe
                f32x2 acc2 = pk_fma(KA.h2[0], hA.h2[0],
                             pk_fma(KA.h2[1], hA.h2[1],
                             pk_fma(KB.h2[0], hB.h2[0],
                             pk_mul(KB.h2[1], hB.h2[1]))));
                const float tot = wave_sum(acc2.x + acc2.y);
                if (l == 0) {
                    hnew[p] = leaky_clip(fmaf(DECAY, hcur[p], tot));
                }
                p = pn; KA = NA; KB = NB;
            }
        }

        // streamed rows [190, R), 2-deep prefetch (empty for iters 3-4)
        while (sp < R) {
            int c2; V4 A2, B2;
            load_row(Mb, sp + 16, R, l, c2, A2, B2);

            const float la = s_la[sp];
            const f32x2 la2 = {la, la};
            f32x2 acc2 = {0.f, 0.f};
            if (l >= c0) {
                f32x2 m0 = clamp2(pk_fma(F2, A0.h2[0], pk_mul(la2, vA.h2[0])));
                f32x2 m1 = clamp2(pk_fma(F2, A0.h2[1], pk_mul(la2, vA.h2[1])));
                acc2 = pk_fma(m0, hA.h2[0], acc2);
                acc2 = pk_fma(m1, hA.h2[1], acc2);
            }
            if (l < 36 && 64 + l >= c0) {
                f32x2 m0 = clamp2(pk_fma(F2, B0.h2[0], pk_mul(la2, vB.h2[0])));
                f32x2 m1 = clamp2(pk_fma(F2, B0.h2[1], pk_mul(la2, vB.h2[1])));
                acc2 = pk_fma(m0, hB.h2[0], acc2);
                acc2 = pk_fma(m1, hB.h2[1], acc2);
            }

            const float tot = wave_sum(acc2.x + acc2.y);
            if (l == 0) {
                hnew[sp] = leaky_clip(fmaf(DECAY, hcur[sp], tot));
            }

            sp += 8; c0 = c1; A0 = A1; B0 = B1; c1 = c2; A1 = A2; B1 = B2;
        }

        // frozen rows carry through
        if (tid >= R && tid < PDIM) hnew[tid] = hcur[tid];
        __syncthreads();
        cur ^= 1;
    }

    if (tid < PDIM) {
        out[b * PDIM + tid] = s_h[cur][tid];
    }
}

extern "C" void kernel_launch(void* const* d_in, const int* in_sizes, int n_in,
                              void* d_out, int out_size, void* d_ws, size_t ws_size,
                              hipStream_t stream) {
    const float* M_prev = (const float*)d_in[0];
    const float* p_inf  = (const float*)d_in[1];
    const float* p_gen  = (const float*)d_in[2];
    const float* query  = (const float*)d_in[3];
    float* out = (float*)d_out;

    const int B = in_sizes[1] / PDIM;   // 512
    hipLaunchKernelGGL(hier_mem_kernel, dim3(B), dim3(512), 0, stream,
                       M_prev, p_inf, p_gen, query, out);
}

// Round 6
// 478.796 us; speedup vs baseline: 1.0297x; 1.0297x over previous
//
#include <hip/hip_runtime.h>

// HierarchicalMemory v8: v7 with the frozen-chunk predicate fix.
// Structure = v5 (473.5us best: 2 blocks/CU, reg rows [0,32) + LDS rows
// [32,78) cached post-clip, packed-fp32, 2-deep prefetch) + frozen-COLUMN
// partials: h_q for q in [R_u, R_{u-1}) is final after iter u-1, so while
// iteration u reads that column band anyway, it reduces the band into
// per-row C_p (LDS) and later iterations skip those columns entirely.
// v7 BUG (absmax 1.01): at t=3, A-chunks l in [50,64) are column-limited
// out of the load (CPREV=50) but the compute predicate was only `l >= c0`,
// so those lanes computed clamp1(la*vA)*hA from a zero A0 and polluted the
// active accumulator. Fix: compute predicate now matches the load predicate
// (`l >= c0 && l < CPREV`); for t<3 CPREV>=70 makes it identical to before.
// Lane l owns columns [4l..4l+3] and [256+4l..256+4l+3]; reduce = 6 DPP adds,
// full sum valid in lane 63 (write from lane 63, no readlane).

#define PDIM 400
#define RREG 4              // register-cached rows: [0, 8*RREG) = [0,32)
#define LROW0 32
#define LROWN 78            // LDS-cached rows [32,78): 46 rows * 1600B = 73.6KB
#define TAIL0 78
#define FORGET 0.9999f
#define LRATE  0.5f
#define DECAY  0.8f
#define SLOPE  0.01f

typedef float f32x2 __attribute__((ext_vector_type(2)));
union V4 { float4 f4; f32x2 h2[2]; };

__device__ __forceinline__ float leaky_clip(float x) {
    x = fminf(fmaxf(x, -1.0f), 1.0f);
    return x > 0.0f ? x : SLOPE * x;
}
__device__ __forceinline__ float clamp1(float x) {   // -> v_med3_f32
    return fminf(fmaxf(x, -1.0f), 1.0f);
}
__device__ __forceinline__ f32x2 pk_mul(f32x2 a, f32x2 b) {
    f32x2 d;
    asm("v_pk_mul_f32 %0, %1, %2" : "=v"(d) : "v"(a), "v"(b));
    return d;
}
__device__ __forceinline__ f32x2 pk_fma(f32x2 a, f32x2 b, f32x2 c) {
    f32x2 d;
    asm("v_pk_fma_f32 %0, %1, %2, %3" : "=v"(d) : "v"(a), "v"(b), "v"(c));
    return d;
}
__device__ __forceinline__ f32x2 pk_add(f32x2 a, f32x2 b) {
    f32x2 d;
    asm("v_pk_add_f32 %0, %1, %2" : "=v"(d) : "v"(a), "v"(b));
    return d;
}
__device__ __forceinline__ f32x2 clamp2(f32x2 x) {
    x.x = clamp1(x.x); x.y = clamp1(x.y); return x;
}

// first masked f4-chunk of row p (chunk = 4-float column group)
__device__ __forceinline__ int c4beg(int p) {
    return (p < 100) ? 0 : (p < 200) ? 25 : (p < 280) ? 50 : (p < 340) ? 70 : 85;
}

// wave64 reduce via DPP; FULL SUM VALID IN LANE 63 (xor1,xor2,half-mirror,
// mirror, bcast15, bcast31 -> lanes 48-63 hold the total).
__device__ __forceinline__ float wave_red63(float x) {
    x += __int_as_float(__builtin_amdgcn_update_dpp(0, __float_as_int(x), 0xB1,  0xf, 0xf, true));
    x += __int_as_float(__builtin_amdgcn_update_dpp(0, __float_as_int(x), 0x4E,  0xf, 0xf, true));
    x += __int_as_float(__builtin_amdgcn_update_dpp(0, __float_as_int(x), 0x141, 0xf, 0xf, true));
    x += __int_as_float(__builtin_amdgcn_update_dpp(0, __float_as_int(x), 0x140, 0xf, 0xf, true));
    x += __int_as_float(__builtin_amdgcn_update_dpp(0, __float_as_int(x), 0x142, 0xf, 0xf, true));
    x += __int_as_float(__builtin_amdgcn_update_dpp(0, __float_as_int(x), 0x143, 0xf, 0xf, true));
    return x;
}

// predicated masked row load limited to chunks < CPREV (CPREV const-folds)
__device__ __forceinline__ void load_row_lim(const float* __restrict__ Mb,
                                             int p, int R, int l, int CPREV,
                                             int& c4, V4& A, V4& B) {
    A.f4 = make_float4(0.f, 0.f, 0.f, 0.f);
    B.f4 = A.f4;
    c4 = 0;
    const int blim = (CPREV >= 100) ? 36 : (CPREV > 64 ? CPREV - 64 : 0);
    if (p < R) {
        c4 = c4beg(p);
        const float* __restrict__ row = Mb + (size_t)p * PDIM;
        if (l >= c4 && l < CPREV)    A.f4 = *(const float4*)(row + 4 * l);
        if (l < blim && 64 + l >= c4) B.f4 = *(const float4*)(row + 256 + 4 * l);
    }
}

__global__ __launch_bounds__(512, 4)
void hier_mem_kernel(const float* __restrict__ M_prev,
                     const float* __restrict__ p_inf,
                     const float* __restrict__ p_gen,
                     const float* __restrict__ query,
                     float* __restrict__ out)
{
    __shared__ float s_mc[LROWN - LROW0][PDIM];   // 73,600 B post-clip M cache
    __shared__ float s_h[2][PDIM];
    __shared__ float s_la[PDIM];
    __shared__ float s_C[PDIM];                   // frozen-column partial per row

    const int b   = blockIdx.x;
    const int tid = threadIdx.x;
    const int l   = tid & 63;   // lane
    const int wid = tid >> 6;   // wave 0..7
    const float* __restrict__ Mb = M_prev + (size_t)b * PDIM * PDIM;

    if (tid < PDIM) {
        const float pi = p_inf[b * PDIM + tid];
        const float pg = p_gen[b * PDIM + tid];
        s_la[tid]   = LRATE * (pi - pg);
        s_h[0][tid] = leaky_clip(query[b * PDIM + tid]);
        s_C[tid]    = 0.f;
    }

    // register-resident b-vector for this lane's fixed columns
    const float4 z4 = make_float4(0.f, 0.f, 0.f, 0.f);
    const float4* __restrict__ pi4 = (const float4*)(p_inf + (size_t)b * PDIM);
    const float4* __restrict__ pg4 = (const float4*)(p_gen + (size_t)b * PDIM);
    V4 vA, vB; vB.f4 = z4;
    {
        const float4 x = pi4[l], y = pg4[l];
        vA.f4 = make_float4(x.x + y.x, x.y + y.y, x.z + y.z, x.w + y.w);
        if (l < 36) {
            const float4 u = pi4[64 + l], v = pg4[64 + l];
            vB.f4 = make_float4(u.x + v.x, u.y + v.y, u.z + v.z, u.w + v.w);
        }
    }
    const f32x2 F2 = {FORGET, FORGET};

    V4 rA[RREG], rB[RREG];   // per-wave register row cache (rows wid+8k, k<RREG)

    __syncthreads();

    // ---------- iteration 0: stream all 400 rows; fill reg + LDS caches ----------
    {
        const float* __restrict__ hcur = s_h[0];
        float* __restrict__ hnew = s_h[1];
        V4 hA, hB; hB.f4 = z4;
        hA.f4 = *(const float4*)(hcur + 4 * l);
        if (l < 36) hB.f4 = *(const float4*)(hcur + 256 + 4 * l);

        int p = wid;
        int c0, c1; V4 A0, B0, A1, B1;
        load_row_lim(Mb, p,     PDIM, l, 100, c0, A0, B0);
        load_row_lim(Mb, p + 8, PDIM, l, 100, c1, A1, B1);

        // rows [0,32): compute + fill register cache (static indices; c4beg==0)
        #pragma unroll
        for (int k = 0; k < RREG; ++k) {
            int c2; V4 A2, B2;
            load_row_lim(Mb, p + 16, PDIM, l, 100, c2, A2, B2);

            const float la = s_la[p];
            const f32x2 la2 = {la, la};
            V4 mA, mB; mA.f4 = z4; mB.f4 = z4;
            mA.h2[0] = clamp2(pk_fma(F2, A0.h2[0], pk_mul(la2, vA.h2[0])));
            mA.h2[1] = clamp2(pk_fma(F2, A0.h2[1], pk_mul(la2, vA.h2[1])));
            if (l < 36) {
                mB.h2[0] = clamp2(pk_fma(F2, B0.h2[0], pk_mul(la2, vB.h2[0])));
                mB.h2[1] = clamp2(pk_fma(F2, B0.h2[1], pk_mul(la2, vB.h2[1])));
            }
            rA[k] = mA; rB[k] = mB;

            f32x2 acc2 = pk_fma(mA.h2[0], hA.h2[0],
                         pk_fma(mA.h2[1], hA.h2[1],
                         pk_fma(mB.h2[0], hB.h2[0],
                         pk_mul(mB.h2[1], hB.h2[1]))));
            const float tot = wave_red63(acc2.x + acc2.y);
            if (l == 63) {
                hnew[p] = leaky_clip(fmaf(DECAY, hcur[p], tot));
            }
            p += 8; c0 = c1; A0 = A1; B0 = B1; c1 = c2; A1 = A2; B1 = B2;
        }

        // rows [32,400): stream; write LDS cache for p < 78
        while (p < PDIM) {
            int c2; V4 A2, B2;
            load_row_lim(Mb, p + 16, PDIM, l, 100, c2, A2, B2);

            const float la = s_la[p];
            const f32x2 la2 = {la, la};
            f32x2 acc2 = {0.f, 0.f};
            V4 mA, mB; mA.f4 = z4; mB.f4 = z4;
            if (l >= c0) {
                mA.h2[0] = clamp2(pk_fma(F2, A0.h2[0], pk_mul(la2, vA.h2[0])));
                mA.h2[1] = clamp2(pk_fma(F2, A0.h2[1], pk_mul(la2, vA.h2[1])));
                acc2 = pk_fma(mA.h2[0], hA.h2[0], acc2);
                acc2 = pk_fma(mA.h2[1], hA.h2[1], acc2);
            }
            if (l < 36 && 64 + l >= c0) {
                mB.h2[0] = clamp2(pk_fma(F2, B0.h2[0], pk_mul(la2, vB.h2[0])));
                mB.h2[1] = clamp2(pk_fma(F2, B0.h2[1], pk_mul(la2, vB.h2[1])));
                acc2 = pk_fma(mB.h2[0], hB.h2[0], acc2);
                acc2 = pk_fma(mB.h2[1], hB.h2[1], acc2);
            }
            if (p < LROWN) {   // rows 32..77: c0==0, full width
                *(float4*)&s_mc[p - LROW0][4 * l] = mA.f4;
                if (l < 36) *(float4*)&s_mc[p - LROW0][256 + 4 * l] = mB.f4;
            }

            const float tot = wave_red63(acc2.x + acc2.y);
            if (l == 63) {
                hnew[p] = leaky_clip(fmaf(DECAY, hcur[p], tot));
            }

            p += 8; c0 = c1; A0 = A1; B0 = B1; c1 = c2; A1 = A2; B1 = B2;
        }
        __syncthreads();   // R=400: no frozen rows
    }

    // ---------- iterations 1..4: reg + LDS rows (full dots) + column-limited tail ----------
    int cur = 1;
    // iter u = t+1:  R = rows computed;  CPREV = read-chunk limit (= R_{u-1}/4)
    // CCUR = active/band split; band chunks [CCUR, CPREV) fold into C_p for
    // rows < PSURV (rows that stream again next iteration).
    const int Rt[4]    = {340, 280, 200, 100};
    const int CPREVt[4]= {100,  85,  70,  50};
    const int CCURt[4] = { 85,  70,  50, 100};
    const int BLIMt[4] = { 36,  21,   6,   0};   // B chunks loaded: l < BLIM
    const int BACTt[4] = { 21,   6,   0,   0};   // B active: l < BACT (rest band)
    const int FOLDt[4] = {  1,   1,   1,   0};
    const int PSURVt[4]= {280, 200, 100,   0};

    #pragma unroll
    for (int t = 0; t < 4; ++t) {
        const int R     = Rt[t];
        const int CPREV = CPREVt[t];
        const int CCUR  = CCURt[t];
        const int BLIM  = BLIMt[t];
        const int BACT  = BACTt[t];
        const int FOLD  = FOLDt[t];
        const int PSURV = PSURVt[t];

        const float* __restrict__ hcur = s_h[cur];
        float* __restrict__ hnew = s_h[cur ^ 1];

        V4 hA, hB; hB.f4 = z4;
        hA.f4 = *(const float4*)(hcur + 4 * l);
        if (l < 36) hB.f4 = *(const float4*)(hcur + 256 + 4 * l);

        // kick off 2-deep column-limited prefetch for the streamed tail FIRST
        int sp = TAIL0 + wid;
        int c0, c1; V4 A0, B0, A1, B1;
        load_row_lim(Mb, sp,     R, l, CPREV, c0, A0, B0);
        load_row_lim(Mb, sp + 8, R, l, CPREV, c1, A1, B1);

        // register-cached rows [0,32): full dots (s_h holds frozen h = final)
        #pragma unroll
        for (int k = 0; k < RREG; ++k) {
            const int p = wid + 8 * k;
            f32x2 acc2 = pk_fma(rA[k].h2[0], hA.h2[0],
                         pk_fma(rA[k].h2[1], hA.h2[1],
                         pk_fma(rB[k].h2[0], hB.h2[0],
                         pk_mul(rB[k].h2[1], hB.h2[1]))));
            const float tot = wave_red63(acc2.x + acc2.y);
            if (l == 63) {
                hnew[p] = leaky_clip(fmaf(DECAY, hcur[p], tot));
            }
        }

        // LDS-cached rows [32,78): full dots from cache, 1-ahead
        {
            int p = LROW0 + wid;
            V4 KA, KB; KB.f4 = z4;
            KA.f4 = *(const float4*)&s_mc[p - LROW0][4 * l];
            if (l < 36) KB.f4 = *(const float4*)&s_mc[p - LROW0][256 + 4 * l];
            while (p < LROWN) {
                const int pn = p + 8;
                V4 NA, NB; NA.f4 = z4; NB.f4 = z4;
                if (pn < LROWN) {
                    NA.f4 = *(const float4*)&s_mc[pn - LROW0][4 * l];
                    if (l < 36) NB.f4 = *(const float4*)&s_mc[pn - LROW0][256 + 4 * l];
                }
                f32x2 acc2 = pk_fma(KA.h2[0], hA.h2[0],
                             pk_fma(KA.h2[1], hA.h2[1],
                             pk_fma(KB.h2[0], hB.h2[0],
                             pk_mul(KB.h2[1], hB.h2[1]))));
                const float tot = wave_red63(acc2.x + acc2.y);
                if (l == 63) {
                    hnew[p] = leaky_clip(fmaf(DECAY, hcur[p], tot));
                }
                p = pn; KA = NA; KB = NB;
            }
        }

        // streamed rows [78, R): cols < CPREV*4 only; band folds into C_p
        while (sp < R) {
            int c2; V4 A2, B2;
            load_row_lim(Mb, sp + 16, R, l, CPREV, c2, A2, B2);

            const float la = s_la[sp];
            const f32x2 la2 = {la, la};
            f32x2 accA = {0.f, 0.f};   // active: chunks < CCUR
            f32x2 accB = {0.f, 0.f};   // band:   chunks in [CCUR, CPREV)
            // A-compute predicate MUST match the A-load predicate (v7 bug:
            // missing `l < CPREV` let unloaded frozen chunks inject
            // clamp1(la*vA)*hA garbage at t=3 where CPREV=50 < 64).
            if (l >= c0 && l < CPREV) {
                f32x2 m0 = clamp2(pk_fma(F2, A0.h2[0], pk_mul(la2, vA.h2[0])));
                f32x2 m1 = clamp2(pk_fma(F2, A0.h2[1], pk_mul(la2, vA.h2[1])));
                f32x2 d  = pk_fma(m0, hA.h2[0], pk_mul(m1, hA.h2[1]));
                if (CCUR >= 64 || l < CCUR) accA = pk_add(accA, d);
                else                        accB = pk_add(accB, d);
            }
            if (l < BLIM && 64 + l >= c0) {   // B chunks (BLIM matches load)
                f32x2 m0 = clamp2(pk_fma(F2, B0.h2[0], pk_mul(la2, vB.h2[0])));
                f32x2 m1 = clamp2(pk_fma(F2, B0.h2[1], pk_mul(la2, vB.h2[1])));
                f32x2 d  = pk_fma(m0, hB.h2[0], pk_mul(m1, hB.h2[1]));
                if (l < BACT) accA = pk_add(accA, d);
                else          accB = pk_add(accB, d);
            }

            const float ta = wave_red63(accA.x + accA.y);
            float tb = 0.f;
            if (FOLD) tb = wave_red63(accB.x + accB.y);
            if (l == 63) {
                const float Cp = s_C[sp];
                if (FOLD && sp < PSURV) s_C[sp] = Cp + tb;
                hnew[sp] = leaky_clip(fmaf(DECAY, hcur[sp], ta + tb + Cp));
            }

            sp += 8; c0 = c1; A0 = A1; B0 = B1; c1 = c2; A1 = A2; B1 = B2;
        }

        // frozen rows carry through
        if (tid >= R && tid < PDIM) hnew[tid] = hcur[tid];
        __syncthreads();
        cur ^= 1;
    }

    if (tid < PDIM) {
        out[b * PDIM + tid] = s_h[cur][tid];
    }
}

extern "C" void kernel_launch(void* const* d_in, const int* in_sizes, int n_in,
                              void* d_out, int out_size, void* d_ws, size_t ws_size,
                              hipStream_t stream) {
    const float* M_prev = (const float*)d_in[0];
    const float* p_inf  = (const float*)d_in[1];
    const float* p_gen  = (const float*)d_in[2];
    const float* query  = (const float*)d_in[3];
    float* out = (float*)d_out;

    const int B = in_sizes[1] / PDIM;   // 512
    hipLaunchKernelGGL(hier_mem_kernel, dim3(B), dim3(512), 0, stream,
                       M_prev, p_inf, p_gen, query, out);
}